// Round 14
// baseline (152.878 us; speedup 1.0000x reference)
//
#include <hip/hip_runtime.h>
#include <math.h>

#define ALPHA 8.3f
// Per phase (16 ch): X = 2 planes x 136 slices (4 rows x 34 cols) x 16 B = 4,352 B
// (granule = 8 consecutive channels, bf16, of one halo pixel)
// W = 18 frags (9 taps x 2 mt) x 64 lanes x 16 B = 18,432 B (v11 verified layout)
#define XSZ   4352
#define WSZ   18432
#define BUFSZ 22784   // XSZ + WSZ; double-buffered = 45,568 B -> 2 blocks/CU (91 KB)

typedef short v8s  __attribute__((ext_vector_type(8)));
typedef float v16f __attribute__((ext_vector_type(16)));
typedef float v4f  __attribute__((ext_vector_type(4)));

static __device__ __forceinline__ unsigned short f2bf(float f) {
    unsigned int u = __float_as_uint(f);
    u = (u + 0x7fffu + ((u >> 16) & 1u)) >> 16;   // RNE
    return (unsigned short)u;
}

static __device__ __forceinline__ void async16(const void* g, void* l) {
    __builtin_amdgcn_global_load_lds(
        (const __attribute__((address_space(1))) unsigned int*)g,
        (__attribute__((address_space(3))) unsigned int*)l, 16, 0, 0);
}

// Weight pre-swizzle, v11 layout (verified in the passing v11 run):
//   granule = (ss*18 + tap*2 + mt)*64 + lane; element j.
//   o = mt*32+(lane&31), cin = ss*16 + (lane>>5)*8 + j  (ss: 0..31 = 16-ch phase)
// Per phase one contiguous 18,432 B region, DMA-copied linearly by the main kernel.
__global__ __launch_bounds__(256) void prep_weights(const float* __restrict__ w,
                                                    unsigned short* __restrict__ wt) {
    const int i = blockIdx.x * 256 + threadIdx.x;
    if (i >= 294912) return;
    const int j    = i & 7;
    const int lane = (i >> 3) & 63;
    const int F    = i >> 9;          // 0..575
    const int mt   = F & 1;
    const int t    = F >> 1;          // 0..287
    const int tap  = t % 9;
    const int ss   = t / 9;           // 0..31
    const int o    = mt * 32 + (lane & 31);
    const int cin  = ss * 16 + (lane >> 5) * 8 + j;
    wt[i] = f2bf(w[(o * 512 + cin) * 9 + tap]);
}

// Main v18: fused cast, 2 INDEPENDENT blocks/CU (v16 was 1 lockstep block -> every
// phase's DMA-drain+barrier stalled the whole CU; all pipes <=18%).
// 512 blocks x 384 thr (6 waves = rt(2) x di(3)); block = (b, 2 rows, 32 cols),
// all 64 Cout (wave computes both mt: acc[3 dj][2 mt] = 96 AGPR, ~160 total regs
// -> fits 170-cap of (384,3), no spill). K=512 over 32 phases of 16 ch.
// X reg-staged from fp32 NCHW (same f2bf RNE -> bit-identical); W via global_load_lds.
// Per-acc K-chain = 32 sequential K16 steps in channel order == v12/v16 (bit-exact).
__global__ __launch_bounds__(384, 3)
void depthconv_v18(const float* __restrict__ x,
                   const float* __restrict__ depth,
                   const unsigned short* __restrict__ wt,
                   float* __restrict__ out) {
    __shared__ __align__(16) char smem[2 * BUFSZ];   // 45,568 B (epilogue reuses)

    // XCD-swizzled decode: xcd owns row-tiles [xcd*4, xcd*4+4) for all (b, wtile)
    const int bx   = blockIdx.x;
    const int xcd  = bx & 7;
    const int i0   = bx >> 3;            // 0..63
    const int wt2  = i0 & 1;
    const int b    = (i0 >> 1) & 7;
    const int ht   = xcd * 4 + (i0 >> 4);   // 0..31
    const int h0   = ht * 2, w0 = wt2 * 32;

    const int tid  = threadIdx.x;
    const int wid  = tid >> 6;           // 0..5
    const int lane = tid & 63;
    const int l31  = lane & 31;
    const int half = lane >> 5;
    const int rt   = wid & 1;            // wave's row within the 2-row tile
    const int di   = wid >> 1;           // kernel row 0..2

    const float* xb = x + (size_t)b * 2097152;   // fp32 NCHW image

    // ---- X staging descriptor: 1 granule/thread (tid < 272), phase-invariant ----
    // granule g (0..271): plane p = g/136 (8-ch group), s = g%136, r = s/34, c = s%34
    // -> pixel (h0-1+r, w0-1+c), channels p*8 + ss*16 .. +8.
    const bool xact = (tid < 272);
    bool xval; int goff; const float* xsrc;
    {
        const int g  = xact ? tid : 0;
        const int p_ = (g >= 136) ? 1 : 0;
        const int s_ = g - p_ * 136;
        const int r_ = s_ / 34, c_ = s_ - r_ * 34;
        const int hh = h0 - 1 + r_, ww = w0 - 1 + c_;
        xval = xact && hh >= 0 && hh < 64 && ww >= 0 && ww < 64;
        goff = g * 16;
        xsrc = xval ? (xb + (size_t)(p_ * 8) * 4096 + hh * 64 + ww) : xb;
    }

    // XLOAD: 8 fp32 loads (invalid -> 0); adv = 16 ch * 4096 px per phase
#define XLOAD(SS, V)                                                             \
    {                                                                            \
        const size_t adv = (size_t)(SS) * 65536;                                 \
        _Pragma("unroll")                                                        \
        for (int e = 0; e < 8; ++e)                                              \
            V[e] = xval ? xsrc[adv + (size_t)e * 4096] : 0.f;                    \
    }
    // XWRITE: f2bf + pack + single ds_write_b128 (linear granules, conflict-free)
#define XWRITE(V, BSEL)                                                          \
    {                                                                            \
        if (xact) {                                                              \
            uint4 u;                                                             \
            u.x = f2bf(V[0]) | ((unsigned)f2bf(V[1]) << 16);                     \
            u.y = f2bf(V[2]) | ((unsigned)f2bf(V[3]) << 16);                     \
            u.z = f2bf(V[4]) | ((unsigned)f2bf(V[5]) << 16);                     \
            u.w = f2bf(V[6]) | ((unsigned)f2bf(V[7]) << 16);                     \
            *(uint4*)(smem + (BSEL) * BUFSZ + goff) = u;                         \
        }                                                                        \
    }
    // W staging: 3 async16/thread (1152 = 3*384 exact), wave-uniform linear dests
#define WISSUE(SS, BSEL)                                                         \
    {                                                                            \
        char* dw = smem + (BSEL) * BUFSZ + XSZ;                                  \
        const char* ws = (const char*)wt + (size_t)(SS) * WSZ;                   \
        _Pragma("unroll")                                                        \
        for (int k = 0; k < 3; ++k)                                              \
            async16(ws + (size_t)(k * 384 + tid) * 16,                           \
                    dw + (k * 384 + tid) * 16);                                  \
    }

    // ---- gates gt[dj] for my row (fp32, OOB depth = 0; verified convention) ----
    float gt[3];
    {
        const float* dp = depth + (size_t)b * 4096;
        const int hq = h0 + rt, wq = w0 + l31;
        const int hn = hq + di - 1;
        const float d0 = dp[hq * 64 + wq];
#pragma unroll
        for (int dj = 0; dj < 3; ++dj) {
            const int wn = wq + dj - 1;
            const float dn = (hn >= 0 && hn < 64 && wn >= 0 && wn < 64)
                                 ? dp[hn * 64 + wn] : 0.f;
            gt[dj] = __expf(-ALPHA * fabsf(d0 - dn));
        }
    }

    v16f am0[3], am1[3];   // acc[dj][mt]: am0 = mt0, am1 = mt1
#pragma unroll
    for (int d = 0; d < 3; ++d)
#pragma unroll
        for (int r = 0; r < 16; ++r) { am0[d][r] = 0.f; am1[d][r] = 0.f; }

    // per-thread LDS read bases (buffer offset added per phase)
    const int aOff = XSZ + (di * 6) * 1024 + lane * 16;          // + (dj*2+mt)*1024
    const int bOff = (half * 136 + (rt + di) * 34 + l31) * 16;   // + dj*16

    // ---- prologue: stage phase 0 ----
    float v[8];
    WISSUE(0, 0);
    XLOAD(0, v);
    XWRITE(v, 0);

    for (int ss = 0; ss < 32; ++ss) {
        __syncthreads();                 // drains W-DMA(ss), fences X writes + prev reads
        const int cur = ss & 1;
        const int nxt = cur ^ 1;
        if (ss < 31) {
            WISSUE(ss + 1, nxt);         // DMA flies under compute(ss)
            XLOAD(ss + 1, v);            // fp32 loads fly under compute(ss)
        }
        const char* ba = smem + cur * BUFSZ + aOff;
        const char* bb = smem + cur * BUFSZ + bOff;
#pragma unroll
        for (int dj = 0; dj < 3; ++dj) {
            const v8s w0v = *(const v8s*)(ba + (dj * 2 + 0) * 1024);
            const v8s w1v = *(const v8s*)(ba + (dj * 2 + 1) * 1024);
            const v8s xv  = *(const v8s*)(bb + dj * 16);
            am0[dj] = __builtin_amdgcn_mfma_f32_32x32x16_bf16(w0v, xv, am0[dj], 0, 0, 0);
            am1[dj] = __builtin_amdgcn_mfma_f32_32x32x16_bf16(w1v, xv, am1[dj], 0, 0, 0);
        }
        if (ss < 31) XWRITE(v, nxt);     // lands before next barrier opens phase ss+1
    }

    // ---- epilogue: gate-combine per tap (v12 order) ----
    float m0[16], m1[16];
#pragma unroll
    for (int r = 0; r < 16; ++r) {
        m0[r] = gt[0] * am0[0][r];
        m0[r] = fmaf(gt[1], am0[1][r], m0[r]);
        m0[r] = fmaf(gt[2], am0[2][r], m0[r]);
        m1[r] = gt[0] * am1[0][r];
        m1[r] = fmaf(gt[1], am1[1][r], m1[r]);
        m1[r] = fmaf(gt[2], am1[2][r], m1[r]);
    }

    // ---- di-reduction in LDS (regions (mt*2+rt) x 4 KB = 16 KB; verified pattern) ----
    __syncthreads();
    float* red = (float*)smem;
    const int rb0 = (0 * 2 + rt) * 1024 + lane * 4;   // mt0 region
    const int rb1 = (1 * 2 + rt) * 1024 + lane * 4;   // mt1 region
#define EPI_STORE(M, RB)                                                         \
    _Pragma("unroll")                                                            \
    for (int qd = 0; qd < 4; ++qd) {                                             \
        v4f vv; vv[0] = M[qd * 4]; vv[1] = M[qd * 4 + 1];                        \
        vv[2] = M[qd * 4 + 2]; vv[3] = M[qd * 4 + 3];                            \
        *(v4f*)&red[(RB) + qd * 256] = vv;                                       \
    }
#define EPI_ADD(M, RB)                                                           \
    _Pragma("unroll")                                                            \
    for (int qd = 0; qd < 4; ++qd) {                                             \
        v4f vv = *(const v4f*)&red[(RB) + qd * 256];                             \
        vv[0] += M[qd * 4];     vv[1] += M[qd * 4 + 1];                          \
        vv[2] += M[qd * 4 + 2]; vv[3] += M[qd * 4 + 3];                          \
        *(v4f*)&red[(RB) + qd * 256] = vv;                                       \
    }
    if (di == 2) { EPI_STORE(m0, rb0) EPI_STORE(m1, rb1) }
    __syncthreads();
    if (di == 1) { EPI_ADD(m0, rb0) EPI_ADD(m1, rb1) }
    __syncthreads();
    if (di == 0) {
        float* ob = out + (size_t)b * 262144 + (h0 + rt) * 64 + w0;
#define EPI_OUT(M, RB, MT)                                                       \
    _Pragma("unroll")                                                            \
    for (int qd = 0; qd < 4; ++qd) {                                             \
        const v4f vv = *(const v4f*)&red[(RB) + qd * 256];                       \
        _Pragma("unroll")                                                        \
        for (int j = 0; j < 4; ++j) {                                            \
            const int rg = qd * 4 + j;                                           \
            const int o = (MT) * 32 + (rg & 3) + 8 * (rg >> 2) + 4 * half;       \
            ob[(size_t)o * 4096 + l31] = M[rg] + vv[j];                          \
        }                                                                        \
    }
        EPI_OUT(m0, rb0, 0) EPI_OUT(m1, rb1, 1)
    }
}

extern "C" void kernel_launch(void* const* d_in, const int* in_sizes, int n_in,
                              void* d_out, int out_size, void* d_ws, size_t ws_size,
                              hipStream_t stream) {
    const float* x      = (const float*)d_in[0];
    const float* depth  = (const float*)d_in[1];
    const float* weight = (const float*)d_in[2];
    float* out = (float*)d_out;

    unsigned short* wtb = (unsigned short*)d_ws;   // 589,824 B weight staging

    prep_weights<<<1152, 256, 0, stream>>>(weight, wtb);
    depthconv_v18<<<512, 384, 0, stream>>>(x, depth, wtb, out);
}